// Round 14
// baseline (83.232 us; speedup 1.0000x reference)
//
#include <hip/hip_runtime.h>
#include <hip/hip_bf16.h>
#include <math.h>

#define IMG 256

typedef __attribute__((ext_vector_type(4))) short short4v;
typedef __attribute__((ext_vector_type(8))) short short8v;
typedef __attribute__((ext_vector_type(4))) float f32x4;
typedef __attribute__((ext_vector_type(2))) float v2f;
typedef _Float16 half2v __attribute__((ext_vector_type(2)));

__device__ __forceinline__ short bf16s(float f) {
    __hip_bfloat16 h = __float2bfloat16(f);
    short s; __builtin_memcpy(&s, &h, 2); return s;
}
__device__ __forceinline__ half2v h2bits(unsigned int u) {
    half2v h; __builtin_memcpy(&h, &u, 4); return h;
}
template <typename T>
__device__ __forceinline__ unsigned int bits4(T v) {
    static_assert(sizeof(T) == 4, "bits4 needs 4-byte type");
    unsigned int u; __builtin_memcpy(&u, &v, 4); return u;
}
__device__ __forceinline__ unsigned int h16b(float f) {
    _Float16 h = (_Float16)f;          // RNE
    unsigned short s; __builtin_memcpy(&s, &h, 2); return (unsigned int)s;
}

// ---------------- Kernel 1: gating conv 7x7 s4 + relu -> per-tile partial logits
// (unchanged from r13)
__global__ __launch_bounds__(256) void gate_mfma_kernel(
    const float* __restrict__ x, const float* __restrict__ Wg,
    const float* __restrict__ We2,
    const float* __restrict__ Wc, const float* __restrict__ Wp,
    float* __restrict__ plog, unsigned int* __restrict__ w2pack)
{
    __shared__ short xs[36 * 136];
    __shared__ float red[4][64];

    const int tile = blockIdx.x;       // 0..15
    const int rt = tile >> 1, ct = tile & 1;
    const int b   = blockIdx.y;
    const int tid = threadIdx.x;

    const float* xb = x + (size_t)b * (IMG * IMG);
    const int gy0 = rt * 32 - 1;
    {
        const int qx = tid & 31;
        const int rb = tid >> 5;
        #pragma unroll
        for (int t = 0; t < 5; ++t) {
            const int r = rb + 8 * t;
            if (r < 36) {
                const int gy = gy0 + r;
                float4 v = make_float4(0.f, 0.f, 0.f, 0.f);
                if (gy >= 0 && gy < IMG)
                    v = *(const float4*)&xb[gy * IMG + 128 * ct + 4 * qx];
                short* p = &xs[r * 136 + 4 * qx + 1];
                p[0] = bf16s(v.x); p[1] = bf16s(v.y); p[2] = bf16s(v.z); p[3] = bf16s(v.w);
            }
        }
    }
    if (tid < 36) {
        const int r = tid, gy = gy0 + r;
        float v = 0.f;
        if (gy >= 0 && gy < IMG && ct == 1) v = xb[gy * IMG + 127];
        xs[r * 136] = bf16s(v);
    }
    if (tid < 36) {
        const int r = tid, gy = gy0 + r;
        float4 v = make_float4(0.f, 0.f, 0.f, 0.f);
        if (gy >= 0 && gy < IMG && ct == 0)
            v = *(const float4*)&xb[gy * IMG + 128];
        short* p = &xs[r * 136 + 129];
        p[0] = bf16s(v.x); p[1] = bf16s(v.y); p[2] = bf16s(v.z); p[3] = bf16s(v.w);
    }

    const int lane = tid & 63;
    const int wv_  = tid >> 6;
    const int m    = lane & 15;
    const int kb   = lane >> 4;

    short8v Bhi[2][4], Blo[2][4];
    #pragma unroll
    for (int s = 0; s < 2; ++s) {
        const int ky = kb + 4 * s;
        #pragma unroll
        for (int nc = 0; nc < 4; ++nc) {
            const int gf = nc * 16 + m;
            short8v bh, bl;
            #pragma unroll
            for (int j = 0; j < 8; ++j) {
                float wv = 0.f;
                if (j < 7 && ky < 7) wv = Wg[gf * 49 + ky * 7 + j];
                const short hi = bf16s(wv);
                const float hif = __uint_as_float(((unsigned int)(unsigned short)hi) << 16);
                bh[j] = hi;
                bl[j] = bf16s(wv - hif);
            }
            Bhi[s][nc] = bh; Blo[s][nc] = bl;
        }
    }

    __syncthreads();

    float rsum[4] = {0.f, 0.f, 0.f, 0.f};
    const f32x4 zero4 = {0.f, 0.f, 0.f, 0.f};

    #pragma unroll 1
    for (int i = 0; i < 4; ++i) {
        const int chunk = wv_ * 4 + i;
        const int r = chunk >> 1, q = chunk & 1;
        short8v A[2];
        #pragma unroll
        for (int s = 0; s < 2; ++s) {
            const int row = 4 * r + kb + 4 * s;
            const short4v* p = (const short4v*)&xs[row * 136 + 64 * q + 4 * m];
            const short4v lo4 = p[0], hi4 = p[1];
            A[s] = __builtin_shufflevector(lo4, hi4, 0, 1, 2, 3, 4, 5, 6, 7);
        }
        #pragma unroll
        for (int nc = 0; nc < 4; ++nc) {
            f32x4 z = __builtin_amdgcn_mfma_f32_16x16x32_bf16(A[0], Bhi[0][nc], zero4, 0, 0, 0);
            z = __builtin_amdgcn_mfma_f32_16x16x32_bf16(A[1], Bhi[1][nc], z, 0, 0, 0);
            z = __builtin_amdgcn_mfma_f32_16x16x32_bf16(A[0], Blo[0][nc], z, 0, 0, 0);
            z = __builtin_amdgcn_mfma_f32_16x16x32_bf16(A[1], Blo[1][nc], z, 0, 0, 0);
            rsum[nc] += fmaxf(z[0], 0.f) + fmaxf(z[1], 0.f) + fmaxf(z[2], 0.f) + fmaxf(z[3], 0.f);
        }
    }

    #pragma unroll
    for (int nc = 0; nc < 4; ++nc) {
        float v = rsum[nc];
        v += __shfl_xor(v, 16);
        v += __shfl_xor(v, 32);
        if (lane < 16) red[wv_][nc * 16 + lane] = v;
    }
    __syncthreads();

    if (tid < 64) {
        const float s = red[0][tid] + red[1][tid] + red[2][tid] + red[3][tid];
        const float fs = s * (1.0f / 4096.0f);
        float lgp[8];
        #pragma unroll
        for (int j = 0; j < 6; ++j) {
            float p = fs * Wc[j * 64 + tid];
            p += __shfl_xor(p, 1);  p += __shfl_xor(p, 2);  p += __shfl_xor(p, 4);
            p += __shfl_xor(p, 8);  p += __shfl_xor(p, 16); p += __shfl_xor(p, 32);
            lgp[j] = p;
        }
        #pragma unroll
        for (int j = 0; j < 2; ++j) {
            float p = fs * Wp[j * 64 + tid];
            p += __shfl_xor(p, 1);  p += __shfl_xor(p, 2);  p += __shfl_xor(p, 4);
            p += __shfl_xor(p, 8);  p += __shfl_xor(p, 16); p += __shfl_xor(p, 32);
            lgp[6 + j] = p;
        }
        if (tid == 0) {
            float* pl = plog + (b * 16 + tile) * 8;
            #pragma unroll
            for (int j = 0; j < 8; ++j) pl[j] = lgp[j];
        }
    }

    if (tile == 0 && b == 0) {
        for (int i = tid; i < 192; i += 256) {
            const int e = i / 24, rem = i - e * 24;
            const int ch = rem / 3, ky = rem - ch * 3;
            const float* wp = We2 + e * 72 + ch * 9 + ky * 3;
            const unsigned int ha = h16b(wp[0]), hb = h16b(wp[1]), hc = h16b(wp[2]);
            w2pack[i * 4 + 0] = ha | (hb << 16);
            w2pack[i * 4 + 1] = hc;
            w2pack[i * 4 + 2] = (ha << 16);
            w2pack[i * 4 + 3] = hb | (hc << 16);
        }
    }
}

// ---------------- Kernel 2: gating decision + two-expert conv-relu-conv -------
// Bank-conflict fix: xs stride 42 floats (was 40), hs stride 38 shorts (19
// dwords, odd -> parity spread). conv2 reads / conv1 h-stores are 4B u32 ops.
// grid (64 tiles of 32x32, 64 batch), 256 threads.
__global__ __launch_bounds__(256) void expert_kernel(
    const float* __restrict__ x,
    const float* __restrict__ We1, const float* __restrict__ be1,
    const unsigned int* __restrict__ w2pack, const float* __restrict__ be2,
    const float* __restrict__ plog,
    const float* __restrict__ bc, const float* __restrict__ bp,
    float* __restrict__ out)
{
    __shared__ float xs[36 * 42];                             // fp32 x tile, stride 42
    __shared__ __align__(16) unsigned short hs[8 * 34 * 38];  // fp16 h, stride 38
    __shared__ int   gsh_i[2];
    __shared__ float gsh_w[2];

    const int tile = blockIdx.x;
    const int b    = blockIdx.y;
    const int ty = tile >> 3, tx = tile & 7;
    const int y0 = ty * 32, x0 = tx * 32;
    const int tid = threadIdx.x;
    const bool interior = (ty != 0) && (ty != 7) && (tx != 0) && (tx != 7);

    // ---- issue gating partial-logit loads EARLY (wave 0, 2 regs only) ----
    float pA = 0.f, pB = 0.f;
    const int jj = tid & 7, tt = tid >> 3;
    if (tid < 64) {
        const float* pl = plog + b * 128;
        pA = pl[(2 * tt) * 8 + jj];
        pB = pl[(2 * tt + 1) * 8 + jj];
    }

    const float* xb = x + (size_t)b * (IMG * IMG);
    if (interior) {
        for (int i = tid; i < 36 * 42; i += 256) {
            int r = i / 42, c = i - r * 42;
            xs[i] = xb[(y0 - 2 + r) * IMG + (x0 - 2 + c)];
        }
    } else {
        for (int i = tid; i < 36 * 42; i += 256) {
            int r = i / 42, c = i - r * 42;
            float v = 0.f;
            if (c < 36) {
                int gy = y0 - 2 + r, gx = x0 - 2 + c;
                if (gy >= 0 && gy < IMG && gx >= 0 && gx < IMG) v = xb[gy * IMG + gx];
            }
            xs[i] = v;
        }
    }

    // ---- finish gating decision (wave 0) ----
    if (tid < 64) {
        float p = pA + pB;
        p += __shfl_xor(p, 8);  p += __shfl_xor(p, 16); p += __shfl_xor(p, 32);
        float lg[8];
        lg[0] = __shfl(p, 0); lg[1] = __shfl(p, 1);
        lg[2] = __shfl(p, 2); lg[3] = __shfl(p, 3);
        lg[4] = __shfl(p, 4); lg[5] = __shfl(p, 5);
        lg[6] = __shfl(p, 6); lg[7] = __shfl(p, 7);
        #pragma unroll
        for (int j = 0; j < 6; ++j) lg[j] += bc[j];
        lg[6] += bp[0]; lg[7] += bp[1];

        const float pm = fmaxf(lg[6], lg[7]);
        const float e0 = expf(lg[6] - pm), e1 = expf(lg[7] - pm);
        const int   pi = (lg[7] > lg[6]) ? 1 : 0;
        const float pv = fmaxf(e0, e1) / (e0 + e1);
        float cm = lg[0];
        #pragma unroll
        for (int j = 1; j < 6; ++j) cm = fmaxf(cm, lg[j]);
        float es = 0.f, ce[6];
        #pragma unroll
        for (int j = 0; j < 6; ++j) { ce[j] = expf(lg[j] - cm); es += ce[j]; }
        int ci = 0; float cbest = lg[0];
        #pragma unroll
        for (int j = 1; j < 6; ++j) if (lg[j] > cbest) { cbest = lg[j]; ci = j; }
        const float cv = ce[ci] / es;

        const float wpv = 0.3f * pv;
        const float wcv = 0.7f * cv;
        const float tot = wpv + wcv + 1e-8f;
        if (tid == 0) {
            gsh_i[0] = pi;
            gsh_i[1] = ci + 2;
            gsh_w[0] = wpv / tot;
            gsh_w[1] = wcv / tot;
        }
    }

    __syncthreads();

    const int ep = __builtin_amdgcn_readfirstlane(gsh_i[0]);
    const int ec = __builtin_amdgcn_readfirstlane(gsh_i[1]);
    const float wA = __uint_as_float(__builtin_amdgcn_readfirstlane(__float_as_uint(gsh_w[0])));
    const float wB = __uint_as_float(__builtin_amdgcn_readfirstlane(__float_as_uint(gsh_w[1])));

    const int r_ = tid >> 3;          // 0..31 output row
    const int c0 = (tid & 7) << 2;    // output col group (4 cols)
    const int c1ch   = tid >> 5;      // conv1: channel 0..7
    const int lane32 = tid & 31;

    float oacc0 = 0.f, oacc1 = 0.f, oacc2 = 0.f, oacc3 = 0.f;

    for (int ei = 0; ei < 2; ++ei) {
        const int   e   = ei ? ec : ep;
        const float wgt = ei ? wB : wA;

        float w1r[9];
        const float* w1p = We1 + e * 72 + c1ch * 9;
        #pragma unroll
        for (int k = 0; k < 9; ++k) w1r[k] = w1p[k];
        const float b1r = be1[e * 8 + c1ch];

        if (ei) __syncthreads();   // prev conv2 reads done before hs overwrite

        // ---- conv1: h = relu(conv(x) + b1) in fp16, 4x4 patch per pass ----
        #pragma unroll 1
        for (int t = 0; t < 3; ++t) {
            const int p = lane32 + 32 * t;
            if (p < 81) {
                const int pr = p / 9;
                const int pc = p - pr * 9;
                const int hy0 = pr << 2;
                const int cb  = pc << 2;      // 0,4,...,32

                v2f a01[4], a23[4];
                #pragma unroll
                for (int q = 0; q < 4; ++q) {
                    a01[q] = (v2f){b1r, b1r};
                    a23[q] = (v2f){b1r, b1r};
                }
                #pragma unroll
                for (int r = 0; r < 6; ++r) {
                    const int row = hy0 + r;
                    if (row < 36) {
                        const float* xr = &xs[row * 42 + cb];
                        const v2f P01 = *(const v2f*)(xr);
                        const v2f P23 = *(const v2f*)(xr + 2);
                        const v2f P45 = *(const v2f*)(xr + 4);
                        const v2f P12 = {P01.y, P23.x};
                        const v2f P34 = {P23.y, P45.x};
                        #pragma unroll
                        for (int q = 0; q < 4; ++q) {
                            const int ky = r - q;
                            if (ky >= 0 && ky < 3) {
                                const float wa = w1r[ky * 3 + 0];
                                const float wb = w1r[ky * 3 + 1];
                                const float wcc = w1r[ky * 3 + 2];
                                const v2f wa2 = {wa, wa}, wb2 = {wb, wb}, wc2 = {wcc, wcc};
                                a01[q] = wa2 * P01 + a01[q];
                                a01[q] = wb2 * P12 + a01[q];
                                a01[q] = wc2 * P23 + a01[q];
                                a23[q] = wa2 * P23 + a23[q];
                                a23[q] = wb2 * P34 + a23[q];
                                a23[q] = wc2 * P45 + a23[q];
                            }
                        }
                    }
                }
                if (interior) {
                    #pragma unroll
                    for (int q = 0; q < 4; ++q) {
                        const int hy = hy0 + q;
                        if (hy < 34) {
                            const unsigned int lo = bits4(
                                __builtin_amdgcn_cvt_pkrtz(fmaxf(a01[q].x, 0.f), fmaxf(a01[q].y, 0.f)));
                            const unsigned int hi = bits4(
                                __builtin_amdgcn_cvt_pkrtz(fmaxf(a23[q].x, 0.f), fmaxf(a23[q].y, 0.f)));
                            unsigned short* hp = &hs[c1ch * 1292 + hy * 38 + cb];
                            *(unsigned int*)hp = lo;
                            if (cb < 32) *(unsigned int*)(hp + 2) = hi;
                        }
                    }
                } else {
                    #pragma unroll
                    for (int q = 0; q < 4; ++q) {
                        const int hy = hy0 + q;
                        if (hy < 34) {
                            const int gy = y0 - 1 + hy;
                            const int gx = x0 - 1 + cb;
                            const bool rowok = (gy >= 0) && (gy < IMG);
                            const float h0 = (rowok && gx >= 0 && gx < IMG) ? fmaxf(a01[q].x, 0.f) : 0.f;
                            const float h1 = (rowok && (gx + 1) < IMG)      ? fmaxf(a01[q].y, 0.f) : 0.f;
                            const float h2 = (rowok && (gx + 2) < IMG)      ? fmaxf(a23[q].x, 0.f) : 0.f;
                            const float h3 = (rowok && (gx + 3) < IMG)      ? fmaxf(a23[q].y, 0.f) : 0.f;
                            const unsigned int lo = bits4(__builtin_amdgcn_cvt_pkrtz(h0, h1));
                            const unsigned int hi = bits4(__builtin_amdgcn_cvt_pkrtz(h2, h3));
                            unsigned short* hp = &hs[c1ch * 1292 + hy * 38 + cb];
                            *(unsigned int*)hp = lo;
                            if (cb < 32) *(unsigned int*)(hp + 2) = hi;
                        }
                    }
                }
            }
        }
        __syncthreads();

        // ---- conv2 via v_dot2_f32_f16: y = conv(h) + b2 (u32 LDS reads) ----
        float a0 = 0.f, a1 = 0.f, a2 = 0.f, a3 = 0.f;
        #pragma unroll
        for (int ch = 0; ch < 8; ++ch) {
            #pragma unroll
            for (int ky = 0; ky < 3; ++ky) {
                const uint4 wp = *(const uint4*)&w2pack[(((e * 8) + ch) * 3 + ky) * 4]; // s_load
                const unsigned short* hp = &hs[ch * 1292 + (r_ + ky) * 38 + c0];
                const unsigned int d0 = *(const unsigned int*)(hp);
                const unsigned int d1 = *(const unsigned int*)(hp + 2);
                const unsigned int d2 = *(const unsigned int*)(hp + 4);
                const half2v P01 = h2bits(d0), P23 = h2bits(d1), P45 = h2bits(d2);
                const half2v p0 = h2bits(wp.x), p1 = h2bits(wp.y), p2 = h2bits(wp.z), p3 = h2bits(wp.w);
                a0 = __builtin_amdgcn_fdot2(p0, P01, a0, false);
                a0 = __builtin_amdgcn_fdot2(p1, P23, a0, false);
                a1 = __builtin_amdgcn_fdot2(p2, P01, a1, false);
                a1 = __builtin_amdgcn_fdot2(p3, P23, a1, false);
                a2 = __builtin_amdgcn_fdot2(p0, P23, a2, false);
                a2 = __builtin_amdgcn_fdot2(p1, P45, a2, false);
                a3 = __builtin_amdgcn_fdot2(p2, P23, a3, false);
                a3 = __builtin_amdgcn_fdot2(p3, P45, a3, false);
            }
        }
        const float b2v = be2[e];
        oacc0 += wgt * (a0 + b2v);
        oacc1 += wgt * (a1 + b2v);
        oacc2 += wgt * (a2 + b2v);
        oacc3 += wgt * (a3 + b2v);
    }

    const float4 o4 = make_float4(oacc0, oacc1, oacc2, oacc3);
    *(float4*)&out[(size_t)b * (IMG * IMG) + (y0 + r_) * IMG + (x0 + c0)] = o4;
}

extern "C" void kernel_launch(void* const* d_in, const int* in_sizes, int n_in,
                              void* d_out, int out_size, void* d_ws, size_t ws_size,
                              hipStream_t stream) {
    const float* x   = (const float*)d_in[0];
    const float* Wg  = (const float*)d_in[1];
    const float* Wc  = (const float*)d_in[2];
    const float* bc  = (const float*)d_in[3];
    const float* Wp  = (const float*)d_in[4];
    const float* bp  = (const float*)d_in[5];
    const float* We1 = (const float*)d_in[6];
    const float* be1 = (const float*)d_in[7];
    const float* We2 = (const float*)d_in[8];
    const float* be2 = (const float*)d_in[9];
    float* out = (float*)d_out;

    float*        plog   = (float*)d_ws;                          // 32 KB
    unsigned int* w2pack = (unsigned int*)((char*)d_ws + 32768);  // 3 KB

    gate_mfma_kernel<<<dim3(16, 64), dim3(256), 0, stream>>>(x, Wg, We2, Wc, Wp, plog, w2pack);
    expert_kernel<<<dim3(64, 64), dim3(256), 0, stream>>>(x, We1, be1, w2pack, be2,
                                                          plog, bc, bp, out);
}

// Round 15
// 73.944 us; speedup vs baseline: 1.1256x; 1.1256x over previous
//
#include <hip/hip_runtime.h>
#include <hip/hip_bf16.h>
#include <math.h>

#define IMG 256

typedef __attribute__((ext_vector_type(4))) short short4v;
typedef __attribute__((ext_vector_type(8))) short short8v;
typedef __attribute__((ext_vector_type(4))) float f32x4;
typedef __attribute__((ext_vector_type(2))) float v2f;
typedef _Float16 half2v __attribute__((ext_vector_type(2)));

__device__ __forceinline__ short bf16s(float f) {
    __hip_bfloat16 h = __float2bfloat16(f);
    short s; __builtin_memcpy(&s, &h, 2); return s;
}
__device__ __forceinline__ half2v h2bits(unsigned int u) {
    half2v h; __builtin_memcpy(&h, &u, 4); return h;
}
template <typename T>
__device__ __forceinline__ unsigned int bits4(T v) {
    static_assert(sizeof(T) == 4, "bits4 needs 4-byte type");
    unsigned int u; __builtin_memcpy(&u, &v, 4); return u;
}
__device__ __forceinline__ unsigned int h16b(float f) {
    _Float16 h = (_Float16)f;          // RNE
    unsigned short s; __builtin_memcpy(&s, &h, 2); return (unsigned int)s;
}

// ---------------- Kernel 1: gating conv 7x7 s4 + relu -> per-tile partial logits
__global__ __launch_bounds__(256) void gate_mfma_kernel(
    const float* __restrict__ x, const float* __restrict__ Wg,
    const float* __restrict__ We2,
    const float* __restrict__ Wc, const float* __restrict__ Wp,
    float* __restrict__ plog, unsigned int* __restrict__ w2pack)
{
    __shared__ short xs[36 * 136];
    __shared__ float red[4][64];

    const int tile = blockIdx.x;       // 0..15
    const int rt = tile >> 1, ct = tile & 1;
    const int b   = blockIdx.y;
    const int tid = threadIdx.x;

    const float* xb = x + (size_t)b * (IMG * IMG);
    const int gy0 = rt * 32 - 1;
    {
        const int qx = tid & 31;
        const int rb = tid >> 5;
        #pragma unroll
        for (int t = 0; t < 5; ++t) {
            const int r = rb + 8 * t;
            if (r < 36) {
                const int gy = gy0 + r;
                float4 v = make_float4(0.f, 0.f, 0.f, 0.f);
                if (gy >= 0 && gy < IMG)
                    v = *(const float4*)&xb[gy * IMG + 128 * ct + 4 * qx];
                short* p = &xs[r * 136 + 4 * qx + 1];
                p[0] = bf16s(v.x); p[1] = bf16s(v.y); p[2] = bf16s(v.z); p[3] = bf16s(v.w);
            }
        }
    }
    if (tid < 36) {
        const int r = tid, gy = gy0 + r;
        float v = 0.f;
        if (gy >= 0 && gy < IMG && ct == 1) v = xb[gy * IMG + 127];
        xs[r * 136] = bf16s(v);
    }
    if (tid < 36) {
        const int r = tid, gy = gy0 + r;
        float4 v = make_float4(0.f, 0.f, 0.f, 0.f);
        if (gy >= 0 && gy < IMG && ct == 0)
            v = *(const float4*)&xb[gy * IMG + 128];
        short* p = &xs[r * 136 + 129];
        p[0] = bf16s(v.x); p[1] = bf16s(v.y); p[2] = bf16s(v.z); p[3] = bf16s(v.w);
    }

    const int lane = tid & 63;
    const int wv_  = tid >> 6;
    const int m    = lane & 15;
    const int kb   = lane >> 4;

    short8v Bhi[2][4], Blo[2][4];
    #pragma unroll
    for (int s = 0; s < 2; ++s) {
        const int ky = kb + 4 * s;
        #pragma unroll
        for (int nc = 0; nc < 4; ++nc) {
            const int gf = nc * 16 + m;
            short8v bh, bl;
            #pragma unroll
            for (int j = 0; j < 8; ++j) {
                float wv = 0.f;
                if (j < 7 && ky < 7) wv = Wg[gf * 49 + ky * 7 + j];
                const short hi = bf16s(wv);
                const float hif = __uint_as_float(((unsigned int)(unsigned short)hi) << 16);
                bh[j] = hi;
                bl[j] = bf16s(wv - hif);
            }
            Bhi[s][nc] = bh; Blo[s][nc] = bl;
        }
    }

    __syncthreads();

    float rsum[4] = {0.f, 0.f, 0.f, 0.f};
    const f32x4 zero4 = {0.f, 0.f, 0.f, 0.f};

    #pragma unroll 1
    for (int i = 0; i < 4; ++i) {
        const int chunk = wv_ * 4 + i;
        const int r = chunk >> 1, q = chunk & 1;
        short8v A[2];
        #pragma unroll
        for (int s = 0; s < 2; ++s) {
            const int row = 4 * r + kb + 4 * s;
            const short4v* p = (const short4v*)&xs[row * 136 + 64 * q + 4 * m];
            const short4v lo4 = p[0], hi4 = p[1];
            A[s] = __builtin_shufflevector(lo4, hi4, 0, 1, 2, 3, 4, 5, 6, 7);
        }
        #pragma unroll
        for (int nc = 0; nc < 4; ++nc) {
            f32x4 z = __builtin_amdgcn_mfma_f32_16x16x32_bf16(A[0], Bhi[0][nc], zero4, 0, 0, 0);
            z = __builtin_amdgcn_mfma_f32_16x16x32_bf16(A[1], Bhi[1][nc], z, 0, 0, 0);
            z = __builtin_amdgcn_mfma_f32_16x16x32_bf16(A[0], Blo[0][nc], z, 0, 0, 0);
            z = __builtin_amdgcn_mfma_f32_16x16x32_bf16(A[1], Blo[1][nc], z, 0, 0, 0);
            rsum[nc] += fmaxf(z[0], 0.f) + fmaxf(z[1], 0.f) + fmaxf(z[2], 0.f) + fmaxf(z[3], 0.f);
        }
    }

    #pragma unroll
    for (int nc = 0; nc < 4; ++nc) {
        float v = rsum[nc];
        v += __shfl_xor(v, 16);
        v += __shfl_xor(v, 32);
        if (lane < 16) red[wv_][nc * 16 + lane] = v;
    }
    __syncthreads();

    if (tid < 64) {
        const float s = red[0][tid] + red[1][tid] + red[2][tid] + red[3][tid];
        const float fs = s * (1.0f / 4096.0f);
        float lgp[8];
        #pragma unroll
        for (int j = 0; j < 6; ++j) {
            float p = fs * Wc[j * 64 + tid];
            p += __shfl_xor(p, 1);  p += __shfl_xor(p, 2);  p += __shfl_xor(p, 4);
            p += __shfl_xor(p, 8);  p += __shfl_xor(p, 16); p += __shfl_xor(p, 32);
            lgp[j] = p;
        }
        #pragma unroll
        for (int j = 0; j < 2; ++j) {
            float p = fs * Wp[j * 64 + tid];
            p += __shfl_xor(p, 1);  p += __shfl_xor(p, 2);  p += __shfl_xor(p, 4);
            p += __shfl_xor(p, 8);  p += __shfl_xor(p, 16); p += __shfl_xor(p, 32);
            lgp[6 + j] = p;
        }
        if (tid == 0) {
            float* pl = plog + (b * 16 + tile) * 8;
            #pragma unroll
            for (int j = 0; j < 8; ++j) pl[j] = lgp[j];
        }
    }

    if (tile == 0 && b == 0) {
        for (int i = tid; i < 192; i += 256) {
            const int e = i / 24, rem = i - e * 24;
            const int ch = rem / 3, ky = rem - ch * 3;
            const float* wp = We2 + e * 72 + ch * 9 + ky * 3;
            const unsigned int ha = h16b(wp[0]), hb = h16b(wp[1]), hc = h16b(wp[2]);
            w2pack[i * 4 + 0] = ha | (hb << 16);
            w2pack[i * 4 + 1] = hc;
            w2pack[i * 4 + 2] = (ha << 16);
            w2pack[i * 4 + 3] = hb | (hc << 16);
        }
    }
}

// ---------------- Kernel 2: gating decision + two-expert conv-relu-conv -------
// r13 layout frozen (xs stride 40, hs stride 36). Only change vs r13: conv1
// row loads are float4+v2f (b128+b64, same bytes) instead of 3x v2f.
// grid (64 tiles of 32x32, 64 batch), 256 threads.
__global__ __launch_bounds__(256) void expert_kernel(
    const float* __restrict__ x,
    const float* __restrict__ We1, const float* __restrict__ be1,
    const unsigned int* __restrict__ w2pack, const float* __restrict__ be2,
    const float* __restrict__ plog,
    const float* __restrict__ bc, const float* __restrict__ bp,
    float* __restrict__ out)
{
    __shared__ float xs[36 * 40];                             // fp32 x tile + halo2
    __shared__ __align__(16) unsigned short hs[8 * 34 * 36];  // fp16 h, stride 36
    __shared__ int   gsh_i[2];
    __shared__ float gsh_w[2];

    const int tile = blockIdx.x;
    const int b    = blockIdx.y;
    const int ty = tile >> 3, tx = tile & 7;
    const int y0 = ty * 32, x0 = tx * 32;
    const int tid = threadIdx.x;
    const bool interior = (ty != 0) && (ty != 7) && (tx != 0) && (tx != 7);

    // ---- issue gating partial-logit loads EARLY (wave 0, 2 regs only) ----
    float pA = 0.f, pB = 0.f;
    const int jj = tid & 7, tt = tid >> 3;
    if (tid < 64) {
        const float* pl = plog + b * 128;
        pA = pl[(2 * tt) * 8 + jj];
        pB = pl[(2 * tt + 1) * 8 + jj];
    }

    const float* xb = x + (size_t)b * (IMG * IMG);
    if (interior) {
        for (int i = tid; i < 36 * 40; i += 256) {
            int r = i / 40, c = i - r * 40;
            xs[i] = xb[(y0 - 2 + r) * IMG + (x0 - 2 + c)];
        }
    } else {
        for (int i = tid; i < 36 * 40; i += 256) {
            int r = i / 40, c = i - r * 40;
            float v = 0.f;
            if (c < 36) {
                int gy = y0 - 2 + r, gx = x0 - 2 + c;
                if (gy >= 0 && gy < IMG && gx >= 0 && gx < IMG) v = xb[gy * IMG + gx];
            }
            xs[i] = v;
        }
    }

    // ---- finish gating decision (wave 0) ----
    if (tid < 64) {
        float p = pA + pB;
        p += __shfl_xor(p, 8);  p += __shfl_xor(p, 16); p += __shfl_xor(p, 32);
        float lg[8];
        lg[0] = __shfl(p, 0); lg[1] = __shfl(p, 1);
        lg[2] = __shfl(p, 2); lg[3] = __shfl(p, 3);
        lg[4] = __shfl(p, 4); lg[5] = __shfl(p, 5);
        lg[6] = __shfl(p, 6); lg[7] = __shfl(p, 7);
        #pragma unroll
        for (int j = 0; j < 6; ++j) lg[j] += bc[j];
        lg[6] += bp[0]; lg[7] += bp[1];

        const float pm = fmaxf(lg[6], lg[7]);
        const float e0 = expf(lg[6] - pm), e1 = expf(lg[7] - pm);
        const int   pi = (lg[7] > lg[6]) ? 1 : 0;
        const float pv = fmaxf(e0, e1) / (e0 + e1);
        float cm = lg[0];
        #pragma unroll
        for (int j = 1; j < 6; ++j) cm = fmaxf(cm, lg[j]);
        float es = 0.f, ce[6];
        #pragma unroll
        for (int j = 0; j < 6; ++j) { ce[j] = expf(lg[j] - cm); es += ce[j]; }
        int ci = 0; float cbest = lg[0];
        #pragma unroll
        for (int j = 1; j < 6; ++j) if (lg[j] > cbest) { cbest = lg[j]; ci = j; }
        const float cv = ce[ci] / es;

        const float wpv = 0.3f * pv;
        const float wcv = 0.7f * cv;
        const float tot = wpv + wcv + 1e-8f;
        if (tid == 0) {
            gsh_i[0] = pi;
            gsh_i[1] = ci + 2;
            gsh_w[0] = wpv / tot;
            gsh_w[1] = wcv / tot;
        }
    }

    __syncthreads();

    const int ep = __builtin_amdgcn_readfirstlane(gsh_i[0]);
    const int ec = __builtin_amdgcn_readfirstlane(gsh_i[1]);
    const float wA = __uint_as_float(__builtin_amdgcn_readfirstlane(__float_as_uint(gsh_w[0])));
    const float wB = __uint_as_float(__builtin_amdgcn_readfirstlane(__float_as_uint(gsh_w[1])));

    const int r_ = tid >> 3;          // 0..31 output row
    const int c0 = (tid & 7) << 2;    // output col group (4 cols)
    const int c1ch   = tid >> 5;      // conv1: channel 0..7
    const int lane32 = tid & 31;

    float oacc0 = 0.f, oacc1 = 0.f, oacc2 = 0.f, oacc3 = 0.f;

    for (int ei = 0; ei < 2; ++ei) {
        const int   e   = ei ? ec : ep;
        const float wgt = ei ? wB : wA;

        float w1r[9];
        const float* w1p = We1 + e * 72 + c1ch * 9;
        #pragma unroll
        for (int k = 0; k < 9; ++k) w1r[k] = w1p[k];
        const float b1r = be1[e * 8 + c1ch];

        if (ei) __syncthreads();   // prev conv2 reads done before hs overwrite

        // ---- conv1: h = relu(conv(x) + b1) in fp16, 4x4 patch per pass ----
        #pragma unroll 1
        for (int t = 0; t < 3; ++t) {
            const int p = lane32 + 32 * t;
            if (p < 81) {
                const int pr = p / 9;
                const int pc = p - pr * 9;
                const int hy0 = pr << 2;
                const int cb  = pc << 2;      // 0,4,...,32

                v2f a01[4], a23[4];
                #pragma unroll
                for (int q = 0; q < 4; ++q) {
                    a01[q] = (v2f){b1r, b1r};
                    a23[q] = (v2f){b1r, b1r};
                }
                #pragma unroll
                for (int r = 0; r < 6; ++r) {
                    const int row = hy0 + r;
                    if (row < 36) {
                        const float* xr = &xs[row * 40 + cb];
                        const float4 xa = *(const float4*)xr;       // b128 (16B aligned)
                        const v2f P45 = *(const v2f*)(xr + 4);      // b64
                        const v2f P01 = {xa.x, xa.y};
                        const v2f P23 = {xa.z, xa.w};
                        const v2f P12 = {xa.y, xa.z};
                        const v2f P34 = {xa.w, P45.x};
                        #pragma unroll
                        for (int q = 0; q < 4; ++q) {
                            const int ky = r - q;
                            if (ky >= 0 && ky < 3) {
                                const float wa = w1r[ky * 3 + 0];
                                const float wb = w1r[ky * 3 + 1];
                                const float wcc = w1r[ky * 3 + 2];
                                const v2f wa2 = {wa, wa}, wb2 = {wb, wb}, wc2 = {wcc, wcc};
                                a01[q] = wa2 * P01 + a01[q];
                                a01[q] = wb2 * P12 + a01[q];
                                a01[q] = wc2 * P23 + a01[q];
                                a23[q] = wa2 * P23 + a23[q];
                                a23[q] = wb2 * P34 + a23[q];
                                a23[q] = wc2 * P45 + a23[q];
                            }
                        }
                    }
                }
                if (interior) {
                    #pragma unroll
                    for (int q = 0; q < 4; ++q) {
                        const int hy = hy0 + q;
                        if (hy < 34) {
                            const unsigned int lo = bits4(
                                __builtin_amdgcn_cvt_pkrtz(fmaxf(a01[q].x, 0.f), fmaxf(a01[q].y, 0.f)));
                            const unsigned int hi = bits4(
                                __builtin_amdgcn_cvt_pkrtz(fmaxf(a23[q].x, 0.f), fmaxf(a23[q].y, 0.f)));
                            unsigned short* hp = &hs[c1ch * 1224 + hy * 36 + cb];
                            if (cb < 32) *(uint2*)hp = make_uint2(lo, hi);
                            else         *(unsigned int*)hp = lo;
                        }
                    }
                } else {
                    #pragma unroll
                    for (int q = 0; q < 4; ++q) {
                        const int hy = hy0 + q;
                        if (hy < 34) {
                            const int gy = y0 - 1 + hy;
                            const int gx = x0 - 1 + cb;
                            const bool rowok = (gy >= 0) && (gy < IMG);
                            const float h0 = (rowok && gx >= 0 && gx < IMG) ? fmaxf(a01[q].x, 0.f) : 0.f;
                            const float h1 = (rowok && (gx + 1) < IMG)      ? fmaxf(a01[q].y, 0.f) : 0.f;
                            const float h2 = (rowok && (gx + 2) < IMG)      ? fmaxf(a23[q].x, 0.f) : 0.f;
                            const float h3 = (rowok && (gx + 3) < IMG)      ? fmaxf(a23[q].y, 0.f) : 0.f;
                            const unsigned int lo = bits4(__builtin_amdgcn_cvt_pkrtz(h0, h1));
                            const unsigned int hi = bits4(__builtin_amdgcn_cvt_pkrtz(h2, h3));
                            unsigned short* hp = &hs[c1ch * 1224 + hy * 36 + cb];
                            if (cb < 32) *(uint2*)hp = make_uint2(lo, hi);
                            else         *(unsigned int*)hp = lo;
                        }
                    }
                }
            }
        }
        __syncthreads();

        // ---- conv2 via v_dot2_f32_f16: y = conv(h) + b2 ----
        float a0 = 0.f, a1 = 0.f, a2 = 0.f, a3 = 0.f;
        #pragma unroll
        for (int ch = 0; ch < 8; ++ch) {
            #pragma unroll
            for (int ky = 0; ky < 3; ++ky) {
                const uint4 wp = *(const uint4*)&w2pack[(((e * 8) + ch) * 3 + ky) * 4]; // s_load
                const unsigned short* hp = &hs[ch * 1224 + (r_ + ky) * 36 + c0];
                const uint2 q4 = *(const uint2*)hp;
                const unsigned int q2 = *(const unsigned int*)(hp + 4);
                const half2v P01 = h2bits(q4.x), P23 = h2bits(q4.y), P45 = h2bits(q2);
                const half2v p0 = h2bits(wp.x), p1 = h2bits(wp.y), p2 = h2bits(wp.z), p3 = h2bits(wp.w);
                a0 = __builtin_amdgcn_fdot2(p0, P01, a0, false);
                a0 = __builtin_amdgcn_fdot2(p1, P23, a0, false);
                a1 = __builtin_amdgcn_fdot2(p2, P01, a1, false);
                a1 = __builtin_amdgcn_fdot2(p3, P23, a1, false);
                a2 = __builtin_amdgcn_fdot2(p0, P23, a2, false);
                a2 = __builtin_amdgcn_fdot2(p1, P45, a2, false);
                a3 = __builtin_amdgcn_fdot2(p2, P23, a3, false);
                a3 = __builtin_amdgcn_fdot2(p3, P45, a3, false);
            }
        }
        const float b2v = be2[e];
        oacc0 += wgt * (a0 + b2v);
        oacc1 += wgt * (a1 + b2v);
        oacc2 += wgt * (a2 + b2v);
        oacc3 += wgt * (a3 + b2v);
    }

    const float4 o4 = make_float4(oacc0, oacc1, oacc2, oacc3);
    *(float4*)&out[(size_t)b * (IMG * IMG) + (y0 + r_) * IMG + (x0 + c0)] = o4;
}

extern "C" void kernel_launch(void* const* d_in, const int* in_sizes, int n_in,
                              void* d_out, int out_size, void* d_ws, size_t ws_size,
                              hipStream_t stream) {
    const float* x   = (const float*)d_in[0];
    const float* Wg  = (const float*)d_in[1];
    const float* Wc  = (const float*)d_in[2];
    const float* bc  = (const float*)d_in[3];
    const float* Wp  = (const float*)d_in[4];
    const float* bp  = (const float*)d_in[5];
    const float* We1 = (const float*)d_in[6];
    const float* be1 = (const float*)d_in[7];
    const float* We2 = (const float*)d_in[8];
    const float* be2 = (const float*)d_in[9];
    float* out = (float*)d_out;

    float*        plog   = (float*)d_ws;                          // 32 KB
    unsigned int* w2pack = (unsigned int*)((char*)d_ws + 32768);  // 3 KB

    gate_mfma_kernel<<<dim3(16, 64), dim3(256), 0, stream>>>(x, Wg, We2, Wc, Wp, plog, w2pack);
    expert_kernel<<<dim3(64, 64), dim3(256), 0, stream>>>(x, We1, be1, w2pack, be2,
                                                          plog, bc, bp, out);
}